// Round 13
// baseline (173.146 us; speedup 1.0000x reference)
//
#include <hip/hip_runtime.h>

typedef unsigned short ushort_t;
typedef unsigned int uint_t;
typedef short bf16x8 __attribute__((ext_vector_type(8)));
typedef float f32x4 __attribute__((ext_vector_type(4)));

#define B_ 128
#define L_ 200
#define D_ 128
#define M_ 64

// ---------- helpers ----------
__device__ __forceinline__ float fast_sigmoid(float x) {
    return 1.f / (1.f + __expf(-x));
}

__device__ __forceinline__ float fast_tanh(float x) {
    float xc = fminf(fmaxf(x, -15.f), 15.f);
    float e = __expf(2.f * xc);
    return (e - 1.f) / (e + 1.f);
}

__device__ __forceinline__ float asf(uint_t u) {
    union { unsigned int u; float f; } x;
    x.u = u;
    return x.f;
}

__device__ __forceinline__ ushort_t f2bf(float f) {
    union { float f; unsigned int u; } x;
    x.f = f;
    unsigned int u = x.u;
    unsigned int r = (u + 0x7FFFu + ((u >> 16) & 1u)) >> 16;  // RNE
    return (ushort_t)r;
}

__device__ __forceinline__ uint4 pack8(float4 a, float4 b) {
    uint4 u;
    u.x = (unsigned)f2bf(a.x) | ((unsigned)f2bf(a.y) << 16);
    u.y = (unsigned)f2bf(a.z) | ((unsigned)f2bf(a.w) << 16);
    u.z = (unsigned)f2bf(b.x) | ((unsigned)f2bf(b.y) << 16);
    u.w = (unsigned)f2bf(b.z) | ((unsigned)f2bf(b.w) << 16);
    return u;
}

// ---------- workspace layout (float offsets) ----------
#define F_WQ   0u          // w as bf16 (B*L, 64)            : 1638400 ushorts
#define F_EAQ  1638400u    // e,a packed bf16 (B*L, 128)     : 3276800 uints
#define F_FKQ  8192000u    // fk f32 (B*L, 128)
#define F_RD   11468800u   // rd as bf16 A-frag pack
#define F_DIFF 14745600u   // que_diff f32 (B*L)
#define F_PACK 14771200u   // weight bf16 pack region
#define WPACK_N 57344
#define FPACK_N 16384

// ---------- K0: pack weights into bf16 MFMA-B fragment order ----------
__global__ __launch_bounds__(256) void k_pack(
    const float* __restrict__ Mk, const float* __restrict__ eW,
    const float* __restrict__ aW, const float* __restrict__ fW,
    ushort_t* __restrict__ Wpack, ushort_t* __restrict__ Fpack)
{
    int i = blockIdx.x * 256 + threadIdx.x;
    if (i < WPACK_N) {
        int g = i >> 9, lane = (i >> 3) & 63, j = i & 7;
        int nt = g >> 2, ks = g & 3;
        int col = nt * 16 + (lane & 15);
        int d = ks * 32 + ((lane >> 4) << 3) + j;
        float v;
        if (col < 64)       v = Mk[col * 128 + d];
        else if (col < 192) v = eW[(col - 64) * 128 + d];
        else if (col < 320) v = aW[(col - 192) * 128 + d];
        else                v = fW[(col - 320) * 256 + 128 + d];  // right half: k
        Wpack[i] = f2bf(v);
    } else if (i < WPACK_N + FPACK_N) {
        int e = i - WPACK_N;
        int g = e >> 9, lane = (e >> 3) & 63, j = e & 7;
        int nt = g >> 2, ks = g & 3;
        int col = nt * 16 + (lane & 15);
        int d = ks * 32 + ((lane >> 4) << 3) + j;
        Fpack[e] = f2bf(fW[col * 256 + d]);  // left half: reads
    }
}

__device__ __forceinline__ void loadB4(const ushort_t* __restrict__ base,
                                       int nt, int lane, bf16x8* b) {
    const ushort_t* p = base + (nt * 256 + lane) * 8;
    b[0] = *(const bf16x8*)(p);
    b[1] = *(const bf16x8*)(p + 512);
    b[2] = *(const bf16x8*)(p + 1024);
    b[3] = *(const bf16x8*)(p + 1536);
}

// ---------- K1: MFMA projections, direct-to-register A-frags, barrier-free ----------
// 400 blocks x 512 thr. Each wave gathers its own A-fragments straight from
// k_emb/v_emb (per-lane regular addresses) — no LDS staging, no __syncthreads.
// waves 0-3 (nh=0): logits nt0-3 + fk nt20-27 (A=k), then wave-local softmax
// waves 4-7 (nh=1): e nt4-11 paired with a nt12-19 (A=k+v_emb[r]), then diff
__global__ __launch_bounds__(512) void k_pre_mfma(
    const int* __restrict__ q, const int* __restrict__ r,
    const float* __restrict__ k_emb, const float* __restrict__ v_emb,
    const ushort_t* __restrict__ Wpack,
    const float* __restrict__ e_b, const float* __restrict__ a_b,
    const float* __restrict__ df_W, const float* __restrict__ df_b,
    ushort_t* __restrict__ wq, uint_t* __restrict__ eaq,
    float* __restrict__ fkq, float* __restrict__ diffq)
{
    __shared__ float slog[64 * 68];   // raw logits (nh0 waves only, wave-local)

    const int tid = threadIdx.x;
    const int pos0 = blockIdx.x * 64;
    const int wave = tid >> 6;
    const int lane = tid & 63;
    const int mt = wave & 3;
    const int nh = wave >> 2;

    const int col = lane & 15;
    const int quad = lane >> 4;
    const int rbase = mt * 16 + quad * 4;

    // --- direct A-frag gather: row = pos0 + mt*16 + col, d = ks*32 + quad*8 ---
    bf16x8 A[4];
    {
        const int arow = pos0 + mt * 16 + col;
        const int qv = q[arow];
        const float4* kp = (const float4*)(k_emb + qv * 128) + quad * 2;
        if (nh == 0) {
            #pragma unroll
            for (int ks = 0; ks < 4; ks++) {
                uint4 u = pack8(kp[ks * 8], kp[ks * 8 + 1]);
                A[ks] = *(bf16x8*)&u;
            }
        } else {
            const int rv = r[arow];
            const float4* vp = (const float4*)(v_emb + rv * 128) + quad * 2;
            #pragma unroll
            for (int ks = 0; ks < 4; ks++) {
                float4 x0 = kp[ks * 8], x1 = kp[ks * 8 + 1];
                float4 y0 = vp[ks * 8], y1 = vp[ks * 8 + 1];
                float4 s0, s1;
                s0.x = x0.x + y0.x; s0.y = x0.y + y0.y;
                s0.z = x0.z + y0.z; s0.w = x0.w + y0.w;
                s1.x = x1.x + y1.x; s1.y = x1.y + y1.y;
                s1.z = x1.z + y1.z; s1.w = x1.w + y1.w;
                uint4 u = pack8(s0, s1);
                A[ks] = *(bf16x8*)&u;
            }
        }
    }

    if (nh == 0) {
        // 12 nts: j 0-3 -> nt j (logits->slog), j 4-11 -> nt j+16 (fk)
        bf16x8 Bb[2][4];
        loadB4(Wpack, 0, lane, Bb[0]);
        #pragma unroll
        for (int j = 0; j < 12; j++) {
            if (j < 11) {
                int jn = j + 1;
                loadB4(Wpack, (jn < 4) ? jn : jn + 16, lane, Bb[jn & 1]);
            }
            f32x4 acc = {0.f, 0.f, 0.f, 0.f};
            #pragma unroll
            for (int ks = 0; ks < 4; ks++)
                acc = __builtin_amdgcn_mfma_f32_16x16x32_bf16(A[ks], Bb[j & 1][ks], acc, 0, 0, 0);
            if (j < 4) {
                #pragma unroll
                for (int reg = 0; reg < 4; reg++)
                    slog[(rbase + reg) * 68 + j * 16 + col] = acc[reg];
            } else {
                int c = (j - 4) * 16 + col;
                #pragma unroll
                for (int reg = 0; reg < 4; reg++)
                    fkq[(pos0 + rbase + reg) * 128 + c] = acc[reg];
            }
        }
        // softmax over own wave's slog rows (wave-local; no barrier needed)
        {
            int row = tid >> 2, ln = tid & 3;
            const float* lr = slog + row * 68 + ln * 16;
            float v[16];
            #pragma unroll
            for (int j = 0; j < 16; j++) v[j] = lr[j];
            float mx = v[0];
            #pragma unroll
            for (int j = 1; j < 16; j++) mx = fmaxf(mx, v[j]);
            mx = fmaxf(mx, __shfl_xor(mx, 1));
            mx = fmaxf(mx, __shfl_xor(mx, 2));
            float s = 0.f;
            #pragma unroll
            for (int j = 0; j < 16; j++) { v[j] = __expf(v[j] - mx); s += v[j]; }
            s += __shfl_xor(s, 1); s += __shfl_xor(s, 2);
            float inv = 1.f / s;
            uint4 u0, u1;
            u0.x = (unsigned)f2bf(v[0] * inv)  | ((unsigned)f2bf(v[1] * inv) << 16);
            u0.y = (unsigned)f2bf(v[2] * inv)  | ((unsigned)f2bf(v[3] * inv) << 16);
            u0.z = (unsigned)f2bf(v[4] * inv)  | ((unsigned)f2bf(v[5] * inv) << 16);
            u0.w = (unsigned)f2bf(v[6] * inv)  | ((unsigned)f2bf(v[7] * inv) << 16);
            u1.x = (unsigned)f2bf(v[8] * inv)  | ((unsigned)f2bf(v[9] * inv) << 16);
            u1.y = (unsigned)f2bf(v[10] * inv) | ((unsigned)f2bf(v[11] * inv) << 16);
            u1.z = (unsigned)f2bf(v[12] * inv) | ((unsigned)f2bf(v[13] * inv) << 16);
            u1.w = (unsigned)f2bf(v[14] * inv) | ((unsigned)f2bf(v[15] * inv) << 16);
            uint4* wout = (uint4*)(wq + (pos0 + row) * 64 + ln * 16);
            wout[0] = u0;
            wout[1] = u1;
        }
    } else {
        bf16x8 Be[2][4], Ba[2][4];
        loadB4(Wpack, 4, lane, Be[0]);
        loadB4(Wpack, 12, lane, Ba[0]);
        #pragma unroll
        for (int i = 0; i < 8; i++) {
            if (i < 7) {
                loadB4(Wpack, 5 + i, lane, Be[(i + 1) & 1]);
                loadB4(Wpack, 13 + i, lane, Ba[(i + 1) & 1]);
            }
            f32x4 ae = {0.f, 0.f, 0.f, 0.f};
            f32x4 aa = {0.f, 0.f, 0.f, 0.f};
            #pragma unroll
            for (int ks = 0; ks < 4; ks++) {
                ae = __builtin_amdgcn_mfma_f32_16x16x32_bf16(A[ks], Be[i & 1][ks], ae, 0, 0, 0);
                aa = __builtin_amdgcn_mfma_f32_16x16x32_bf16(A[ks], Ba[i & 1][ks], aa, 0, 0, 0);
            }
            int c = i * 16 + col;
            float ebv = e_b[c], abv = a_b[c];
            #pragma unroll
            for (int reg = 0; reg < 4; reg++) {
                float ev = fast_sigmoid(ae[reg] + ebv);
                float av = fast_tanh(aa[reg] + abv);
                eaq[(pos0 + rbase + reg) * 128 + c] =
                    (unsigned)f2bf(ev) | ((unsigned)f2bf(av) << 16);
            }
        }
        // que_diff: direct f32 dot, 4 threads/row (threads 256-511)
        {
            int t2 = tid - 256;
            int row = t2 >> 2, ln = t2 & 3;
            int pos = pos0 + row;
            int qv = q[pos];
            const float4* kp = (const float4*)(k_emb + qv * 128) + ln * 8;
            const float4* dfp = (const float4*)df_W + ln * 8;
            float s = 0.f;
            #pragma unroll
            for (int j = 0; j < 8; j++) {
                float4 a = kp[j], b = dfp[j];
                s = fmaf(a.x, b.x, fmaf(a.y, b.y, fmaf(a.z, b.z, fmaf(a.w, b.w, s))));
            }
            s += __shfl_xor(s, 1); s += __shfl_xor(s, 2);
            if (ln == 0) diffq[pos] = fast_tanh(s + df_b[0]);
        }
    }
}

// ---------- K2: scan — 16-way m-split, 4 waves/SIMD, barrier-free ----------
// grid 1024: b = blk>>3, dq = blk&7 (16 d). Block 256 thr = 4 waves (4 d each).
// lane = s*4+dl: s = m-quad (Mv[4]), dl = d. Reduce = shfl_xor 4/8/16/32.
// s==0 lanes store reads as bf16 in MFMA A-frag order for k_final.
#define SC_PRE(wX, eX, cN)                                                 \
    _Pragma("unroll")                                                      \
    for (int tt = 0; tt < 8; tt++) {                                       \
        wX[tt] = *(const uint2*)(wb + ((cN) * 8 + tt) * 64);               \
        eX[tt] = eab[((cN) * 8 + tt) * 128];                               \
    }

#define SC_CMP(wX, eX, cN)                                                 \
    _Pragma("unroll")                                                      \
    for (int tt = 0; tt < 8; tt++) {                                       \
        uint2 wu = wX[tt];                                                 \
        uint_t eu = eX[tt];                                                \
        float ev = asf(eu << 16), av = asf(eu & 0xFFFF0000u), ne = -ev;    \
        float g0 = asf(wu.x << 16), g1 = asf(wu.x & 0xFFFF0000u);          \
        float g2 = asf(wu.y << 16), g3 = asf(wu.y & 0xFFFF0000u);          \
        float r0, r1;                                                      \
        r0 = g0 * Mv[0];                                                   \
        r1 = g1 * Mv[1];                                                   \
        r0 = fmaf(g2, Mv[2], r0); r1 = fmaf(g3, Mv[3], r1);                \
        Mv[0] = fmaf(g0, fmaf(ne, Mv[0], av), Mv[0]);                      \
        Mv[1] = fmaf(g1, fmaf(ne, Mv[1], av), Mv[1]);                      \
        Mv[2] = fmaf(g2, fmaf(ne, Mv[2], av), Mv[2]);                      \
        Mv[3] = fmaf(g3, fmaf(ne, Mv[3], av), Mv[3]);                      \
        float rd = r0 + r1;                                                \
        rd += __shfl_xor(rd, 4);                                           \
        rd += __shfl_xor(rd, 8);                                           \
        rd += __shfl_xor(rd, 16);                                          \
        rd += __shfl_xor(rd, 32);                                          \
        if (s == 0) {                                                      \
            int pos = pos_base + (cN) * 8 + tt;                            \
            int idx = (((pos >> 4) * 4 + ksd) * 64                         \
                       + (q8d * 16 + (pos & 15))) * 8 + jd;                \
            rdpack[idx] = f2bf(rd);                                        \
        }                                                                  \
    }

__global__ __launch_bounds__(256) void k_scan(
    const ushort_t* __restrict__ wq, const uint_t* __restrict__ eaq,
    const float* __restrict__ Mv0, ushort_t* __restrict__ rdpack)
{
    const int tid = threadIdx.x;
    const int b = blockIdx.x >> 3;
    const int dq = blockIdx.x & 7;
    const int wv = tid >> 6;      // wave -> 4-d chunk
    const int lane = tid & 63;
    const int s = lane >> 2;      // m-quad (0..15)
    const int dl = lane & 3;
    const int d = dq * 16 + wv * 4 + dl;

    float Mv[4];
    #pragma unroll
    for (int j = 0; j < 4; j++) Mv[j] = Mv0[(s * 4 + j) * D_ + d];

    const ushort_t* wb = wq + b * (L_ * M_) + s * 4;
    const uint_t* eab = eaq + b * (L_ * 128) + d;

    const int pos_base = b * L_;
    const int ksd = d >> 5;
    const int q8d = (d >> 3) & 3;
    const int jd = d & 7;

    uint2 wA[8], wB[8];
    uint_t eA[8], eB[8];

    SC_PRE(wA, eA, 0);
    for (int c = 0; c < 12; c++) {
        SC_PRE(wB, eB, 2 * c + 1);
        SC_CMP(wA, eA, 2 * c);
        SC_PRE(wA, eA, 2 * c + 2);
        SC_CMP(wB, eB, 2 * c + 1);
    }
    SC_CMP(wA, eA, 24);
}

// ---------- K3: MFMA f-GEMM, A-frags direct from rdpack; fused ab/out ----------
__global__ __launch_bounds__(512) void k_final_mfma(
    const ushort_t* __restrict__ rdpack, const float* __restrict__ fkq,
    const float* __restrict__ diffq, const ushort_t* __restrict__ Fpack,
    const float* __restrict__ f_b, const float* __restrict__ ab_W,
    const float* __restrict__ ab_b, float* __restrict__ out)
{
    __shared__ float sab[64 * 2];

    const int tid = threadIdx.x;
    const int pos0 = blockIdx.x * 64;
    const int wave = tid >> 6;
    const int lane = tid & 63;
    const int mt = wave & 3;        // m-tile
    const int half = wave >> 2;     // nt half

    const int col = lane & 15;
    const int quad = lane >> 4;
    const int rbase = mt * 16 + quad * 4;

    bf16x8 A[4];
    {
        const ushort_t* rp = rdpack + (blockIdx.x * 4 + mt) * 2048 + lane * 8;
        #pragma unroll
        for (int ks = 0; ks < 4; ks++)
            A[ks] = *(const bf16x8*)(rp + ks * 512);
    }

    float fkv[16];
    #pragma unroll
    for (int i = 0; i < 4; i++)
        #pragma unroll
        for (int reg = 0; reg < 4; reg++)
            fkv[i * 4 + reg] = fkq[(pos0 + rbase + reg) * 128 + (half * 4 + i) * 16 + col];

    float abacc[4] = {0.f, 0.f, 0.f, 0.f};

    bf16x8 Bb[2][4];
    loadB4(Fpack, half * 4, lane, Bb[0]);
    #pragma unroll
    for (int i = 0; i < 4; i++) {
        if (i < 3) loadB4(Fpack, half * 4 + i + 1, lane, Bb[(i + 1) & 1]);
        f32x4 acc = {0.f, 0.f, 0.f, 0.f};
        #pragma unroll
        for (int ks = 0; ks < 4; ks++)
            acc = __builtin_amdgcn_mfma_f32_16x16x32_bf16(A[ks], Bb[i & 1][ks], acc, 0, 0, 0);
        int c = (half * 4 + i) * 16 + col;
        float fb = f_b[c];
        float abw = ab_W[c];
        #pragma unroll
        for (int reg = 0; reg < 4; reg++) {
            float fv = fast_tanh(acc[reg] + fkv[i * 4 + reg] + fb);
            abacc[reg] = fmaf(abw, fv, abacc[reg]);
        }
    }

    #pragma unroll
    for (int reg = 0; reg < 4; reg++) {
        float v = abacc[reg];
        v += __shfl_xor(v, 1); v += __shfl_xor(v, 2);
        v += __shfl_xor(v, 4); v += __shfl_xor(v, 8);
        abacc[reg] = v;
    }
    if (col == 0) {
        #pragma unroll
        for (int reg = 0; reg < 4; reg++)
            sab[(rbase + reg) * 2 + half] = abacc[reg];
    }
    __syncthreads();
    if (tid < 64) {
        float ab = fast_tanh(sab[tid * 2] + sab[tid * 2 + 1] + ab_b[0]);
        int pos = pos0 + tid;
        out[pos] = fast_sigmoid(3.f * ab - diffq[pos]);
    }
}

// ---------- launch ----------
extern "C" void kernel_launch(void* const* d_in, const int* in_sizes, int n_in,
                              void* d_out, int out_size, void* d_ws, size_t ws_size,
                              hipStream_t stream)
{
    const int*   q     = (const int*)d_in[0];
    const int*   r     = (const int*)d_in[1];
    const float* k_emb = (const float*)d_in[2];
    const float* v_emb = (const float*)d_in[3];
    const float* Mk    = (const float*)d_in[4];
    const float* Mv0   = (const float*)d_in[5];
    const float* f_W   = (const float*)d_in[6];
    const float* f_b   = (const float*)d_in[7];
    const float* e_W   = (const float*)d_in[8];
    const float* e_b   = (const float*)d_in[9];
    const float* a_W   = (const float*)d_in[10];
    const float* a_b   = (const float*)d_in[11];
    const float* ab_W  = (const float*)d_in[12];
    const float* ab_b  = (const float*)d_in[13];
    const float* df_W  = (const float*)d_in[14];
    const float* df_b  = (const float*)d_in[15];

    float* ws = (float*)d_ws;
    float* out = (float*)d_out;
    ushort_t* wq = (ushort_t*)(ws + F_WQ);
    uint_t* eaq = (uint_t*)(ws + F_EAQ);
    ushort_t* Wpack = (ushort_t*)(ws + F_PACK);
    ushort_t* Fpack = Wpack + WPACK_N;
    ushort_t* rdpack = (ushort_t*)(ws + F_RD);

    // K0: pack weights to bf16 fragment layout
    k_pack<<<288, 256, 0, stream>>>(Mk, e_W, a_W, f_W, Wpack, Fpack);

    // K1: MFMA projections, direct A-frag gather, barrier-free (400 x 512)
    k_pre_mfma<<<400, 512, 0, stream>>>(
        q, r, k_emb, v_emb, Wpack, e_b, a_b, df_W, df_b,
        wq, eaq, ws + F_FKQ, ws + F_DIFF);

    // K2: scan (128 b x 8 dq, 16-way m-split, 4 waves/SIMD)
    k_scan<<<1024, 256, 0, stream>>>(wq, eaq, Mv0, rdpack);

    // K3: final MFMA + epilogue (400 blocks x 8 waves)
    k_final_mfma<<<400, 512, 0, stream>>>(
        rdpack, ws + F_FKQ, ws + F_DIFF, Fpack,
        f_b, ab_W, ab_b, out);
}